// Round 11
// baseline (650.028 us; speedup 1.0000x reference)
//
#include <hip/hip_runtime.h>

#define HH 51
#define TT 256
#define NB 8
#define L2E 1.442695041f

typedef __attribute__((ext_vector_type(8))) _Float16 half8;
typedef __attribute__((ext_vector_type(4))) float   floatx4;

#define MFMA16F(A,B,C) __builtin_amdgcn_mfma_f32_16x16x32_f16((A),(B),(C),0,0,0)

__device__ __forceinline__ float rcp_fast(float x) { return __builtin_amdgcn_rcpf(x); }
#if __has_builtin(__builtin_amdgcn_exp2f)
__device__ __forceinline__ float exp2_fast(float x) { return __builtin_amdgcn_exp2f(x); }
#else
__device__ __forceinline__ float exp2_fast(float x) { return __expf(0.69314718056f * x); }
#endif
__device__ __forceinline__ unsigned short f2h_bits(float v) {
    return __builtin_bit_cast(unsigned short, (_Float16)v);
}

// ------------- weight pre-pack: IDENTICAL to round 10 (verified) ---------
// B-frag 16x16x32_f16: lane holds B[k=(lane>>4)*8+jj][n=lane&15], 8 halves.
// ids: cell1 ((g*4+U)*2+s)*2+hl (64) | cell2 64+((g*4+U)*4+s)*2+hl (128) |
//      head 192+s*2+hl (4). ws = 196*64*16 B.
// K-columns: cell1 k<51=Whh1, k=51=bias1, k=52/53=Wih1 (x hi/lo).
//            cell2 h1-half k<51=Wih2, k=51=bias2; h2-half k2<51=Whh2.
//            head n=0: k<51=Wlin, k=51=blin.
// Gate scales folded: i,f,o *L2E ; g *2*L2E ; head unscaled. hl=1 = residual.
__global__ void lstm_prep(const float* __restrict__ Whh1, const float* __restrict__ Wih1,
                          const float* __restrict__ bih1, const float* __restrict__ bhh1,
                          const float* __restrict__ Wih2, const float* __restrict__ Whh2,
                          const float* __restrict__ bih2, const float* __restrict__ bhh2,
                          const float* __restrict__ Wlin, const float* __restrict__ blin,
                          uint4* __restrict__ frags) {
    int tid = blockIdx.x * blockDim.x + threadIdx.x;
    if (tid >= 196 * 64) return;
    int f = tid >> 6, lane = tid & 63;
    int n = lane & 15, qq = lane >> 4;
    int hl, s, tau, cell;
    if (f < 64)       { cell = 1; int r = f;       hl = r & 1; r >>= 1; s = r & 1; tau = r >> 1; }
    else if (f < 192) { cell = 2; int r = f - 64;  hl = r & 1; r >>= 1; s = r & 3; tau = r >> 2; }
    else              { cell = 3; int r = f - 192; hl = r & 1; s = r >> 1; tau = 0; }
    int g = tau >> 2, U = tau & 3, u = U * 16 + n;
    float sc = (cell == 3) ? 1.0f : ((g == 2) ? 2.0f * L2E : L2E);
    unsigned int dw[4];
    for (int d = 0; d < 4; d++) {
        unsigned int packed = 0;
        for (int e = 0; e < 2; e++) {
            int jj = d * 2 + e;
            int k = s * 32 + qq * 8 + jj;
            float val = 0.f;
            if (cell == 1) {
                if (u < HH) {
                    if (k < HH)       val = Whh1[(g * HH + u) * HH + k];
                    else if (k == 51) val = bih1[g * HH + u] + bhh1[g * HH + u];
                    else              val = Wih1[g * HH + u];   // k=52,53
                }
            } else if (cell == 2) {
                if (u < HH) {
                    if (k < 64) {
                        if (k < HH)       val = Wih2[(g * HH + u) * HH + k];
                        else if (k == 51) val = bih2[g * HH + u] + bhh2[g * HH + u];
                    } else {
                        int k2 = k - 64;
                        if (k2 < HH) val = Whh2[(g * HH + u) * HH + k2];
                    }
                }
            } else {
                if (n == 0) {
                    if (k < HH)       val = Wlin[k];
                    else if (k == 51) val = blin[0];
                }
            }
            val *= sc;
            _Float16 hi = (_Float16)val;
            unsigned short bits;
            if (hl) { float lo = val - (float)hi; bits = f2h_bits(lo); }
            else    { bits = __builtin_bit_cast(unsigned short, hi); }
            packed |= ((unsigned int)bits) << (16 * e);
        }
        dw[d] = packed;
    }
    frags[f * 64 + lane] = make_uint4(dw[0], dw[1], dw[2], dw[3]);
}

// -------------------------------------------------------------------------
// Merged-role one-barrier LSTM, 2 WGs/CU edition.
// 256 thr = 4 waves/WG, NB=8 batch/WG, grid 512 -> 2 independent WGs per CU
// (two barrier domains fill each other's dependency stalls).
// Wave w owns u-tile U=w for BOTH cells (+ head rotated (IT&3)==w):
//   epoch IT: shared reads a0,a1=h1(IT-1), a2,a3=h2(IT-2);
//   head -> out(IT-2); cell1 (16 MFMA) -> h1(IT); cell2 (32 MFMA) -> h2(IT-1).
// MFMA 16x16 tiles half-empty (rows 8..15 zero) - MFMA pipe is ~10% busy,
// the waste is free; h rows 8..15 stay zero (stores guarded bb<8).
// h layout/swizzle/parities identical to round 10 (verified).
// Head B-frags fetched from L2 per head-epoch (saves 16 stationary regs).
// -------------------------------------------------------------------------
__launch_bounds__(256, 2)
__global__ void lstm_main(const float* __restrict__ input,
                          const uint4* __restrict__ frags,
                          float* __restrict__ out) {
    __shared__ __align__(16) unsigned int h1[2][16][36];
    __shared__ __align__(16) unsigned int h2[2][16][36];
    __shared__ __align__(16) float xb[(TT + 1) * NB];    // [t][b], row TT = 0

    const int tid  = threadIdx.x;
    const int lane = tid & 63;
    const int w    = tid >> 6;          // 0..3
    const int l15  = lane & 15;
    const int q    = lane >> 4;
    const int b0g  = blockIdx.x * NB;
    const int uc   = w * 16 + l15;      // owned u (C-layout col)
    const bool uok = (uc < HH);

    for (int i = tid; i < 2 * 16 * 36; i += 256) {
        ((unsigned*)h1)[i] = 0; ((unsigned*)h2)[i] = 0;
    }
    for (int c = 0; c < 2; c++) {
        int flat = tid + c * 256;                        // 512 float4 rows
        int b = flat >> 6, t0 = (flat & 63) * 4;
        float4 v = *(const float4*)&input[(size_t)(b0g + b) * TT + t0];
        xb[(t0 + 0) * NB + b] = v.x; xb[(t0 + 1) * NB + b] = v.y;
        xb[(t0 + 2) * NB + b] = v.z; xb[(t0 + 3) * NB + b] = v.w;
    }
    if (tid < NB) xb[TT * NB + tid] = 0.f;
    __syncthreads();
    if (tid < NB) {                     // hooks in h1 parity 1 (b < 8 only)
        int b = tid;
        int wi51 = ((25 + 4 * (b >> 1)) & 31) * 2 + 1;   // u=51 (bias col)
        int wi52 = ((26 + 4 * (b >> 1)) & 31) * 2 + 0;   // u=52 (x hi)
        int wi53 = ((26 + 4 * (b >> 1)) & 31) * 2 + 1;   // u=53 (x lo)
        ((unsigned short*)&h1[1][b][0])[wi51] = 0x3C00;  // fp16(1.0)
        float x0 = input[(size_t)(b0g + b) * TT];
        _Float16 xh = (_Float16)x0;
        ((unsigned short*)&h1[1][b][0])[wi52] = __builtin_bit_cast(unsigned short, xh);
        ((unsigned short*)&h1[1][b][0])[wi53] = f2h_bits(x0 - (float)xh);
    }

    // weight-stationary fragments: cell1 (16) + cell2 (32) per wave
    half8 fr1[16], fr2[32];
#pragma unroll
    for (int g = 0; g < 4; g++) {
        int tau = g * 4 + w;
#pragma unroll
        for (int s = 0; s < 2; s++) {
            fr1[g * 4 + s * 2 + 0] = __builtin_bit_cast(half8, frags[((tau * 2 + s) * 2 + 0) * 64 + lane]);
            fr1[g * 4 + s * 2 + 1] = __builtin_bit_cast(half8, frags[((tau * 2 + s) * 2 + 1) * 64 + lane]);
        }
#pragma unroll
        for (int s = 0; s < 4; s++) {
            fr2[g * 8 + s * 2 + 0] = __builtin_bit_cast(half8, frags[(64 + (tau * 4 + s) * 2 + 0) * 64 + lane]);
            fr2[g * 8 + s * 2 + 1] = __builtin_bit_cast(half8, frags[(64 + (tau * 4 + s) * 2 + 1) * 64 + lane]);
        }
    }
    floatx4 zacc = {0.f, 0.f, 0.f, 0.f};
    float cst1[4] = {0.f, 0.f, 0.f, 0.f};
    float cst2[4] = {0.f, 0.f, 0.f, 0.f};
    const int baseA = (q * 4 + 4 * (l15 >> 1)) & 31;
    const int baseB = (baseA + 16) & 31;

    __syncthreads();

#define GTAIL(DG, FG, SGN)                                                      \
    _Pragma("unroll")                                                           \
    for (int r = 0; r < 4; r++) {                                               \
        float e = exp2_fast(SGN (DG)[r]);                                       \
        (FG)[r] = rcp_fast(1.0f + e);                                           \
    }

#define STEP(IT, P)                                                             \
    do {                                                                        \
        half8 a0 = *(const half8*)&h1[1 - (P)][l15][baseA];  /* h1(IT-1) */     \
        half8 a1 = *(const half8*)&h1[1 - (P)][l15][baseB];                     \
        half8 a2 = *(const half8*)&h2[(P)][l15][baseA];      /* h2(IT-2) */     \
        half8 a3 = *(const half8*)&h2[(P)][l15][baseB];                         \
        /* -------- head (rotated): out(IT-2) = Wlin.h2(IT-2)+blin -------- */  \
        if ((IT) >= 2 && (((IT) & 3) == w)) {                                   \
            half8 hf0 = __builtin_bit_cast(half8, frags[(192 + 0) * 64 + lane]);\
            half8 hf1 = __builtin_bit_cast(half8, frags[(192 + 1) * 64 + lane]);\
            half8 hf2 = __builtin_bit_cast(half8, frags[(192 + 2) * 64 + lane]);\
            half8 hf3 = __builtin_bit_cast(half8, frags[(192 + 3) * 64 + lane]);\
            floatx4 ho;                                                         \
            ho = MFMA16F(a2, hf0, zacc); ho = MFMA16F(a2, hf1, ho);             \
            ho = MFMA16F(a3, hf2, ho);   ho = MFMA16F(a3, hf3, ho);             \
            if (l15 == 0 && q < 2) {                                            \
                _Pragma("unroll")                                               \
                for (int r = 0; r < 4; r++)                                     \
                    out[(size_t)(b0g + q * 4 + r) * TT + ((IT) - 2)] = ho[r];   \
            }                                                                   \
        }                                                                       \
        /* -------- cell1: h1(IT) ----------------------------------------- */  \
        if ((IT) <= TT - 1) {                                                   \
            float4 xn = {0.f, 0.f, 0.f, 0.f};                                   \
            if (uc >= HH && q < 2) xn = *(const float4*)&xb[((IT) + 1) * NB + q * 4]; \
            floatx4 d0, d1, d2, d3;                                             \
            d0 = MFMA16F(a0, fr1[0],  zacc); d0 = MFMA16F(a0, fr1[1],  d0);     \
            d1 = MFMA16F(a0, fr1[4],  zacc); d1 = MFMA16F(a0, fr1[5],  d1);     \
            d2 = MFMA16F(a0, fr1[8],  zacc); d2 = MFMA16F(a0, fr1[9],  d2);     \
            d3 = MFMA16F(a0, fr1[12], zacc); d3 = MFMA16F(a0, fr1[13], d3);     \
            d0 = MFMA16F(a1, fr1[2],  d0);   d0 = MFMA16F(a1, fr1[3],  d0);     \
            d1 = MFMA16F(a1, fr1[6],  d1);   d1 = MFMA16F(a1, fr1[7],  d1);     \
            d2 = MFMA16F(a1, fr1[10], d2);   d2 = MFMA16F(a1, fr1[11], d2);     \
            d3 = MFMA16F(a1, fr1[14], d3);   d3 = MFMA16F(a1, fr1[15], d3);     \
            floatx4 f0, f1, f2, f3;                                             \
            GTAIL(d0, f0, -) GTAIL(d1, f1, -) GTAIL(d2, f2, +) GTAIL(d3, f3, -) \
            _Pragma("unroll")                                                   \
            for (int r = 0; r < 4; r++) {                                       \
                float tgs = fmaf(-4.0f * L2E, f2[r], 2.0f * L2E);               \
                float cn  = fmaf(f1[r], cst1[r], f0[r] * tgs);                  \
                cst1[r] = cn;                                                   \
                float th = fmaf(-2.0f, rcp_fast(1.0f + exp2_fast(cn)), 1.0f);   \
                float hv = f3[r] * th;                                          \
                hv = uok ? hv                                                   \
                         : (uc == 51 ? 1.0f                                     \
                         : (uc == 52 ? xn[r]                                    \
                         : (uc == 53 ? xn[r] - (float)(_Float16)xn[r] : 0.f))); \
                int bb = q * 4 + r;                                             \
                if (bb < NB) {                                                  \
                    int wi = (((uc >> 1) + 4 * (bb >> 1)) & 31) * 2 + (uc & 1); \
                    ((unsigned short*)&h1[(P)][bb][0])[wi] = f2h_bits(hv);      \
                }                                                               \
            }                                                                   \
        }                                                                       \
        /* -------- cell2: h2(IT-1) --------------------------------------- */  \
        if ((IT) >= 1 && (IT) <= TT) {                                          \
            floatx4 e0, e1, e2, e3;                                             \
            e0 = MFMA16F(a0, fr2[0],  zacc); e0 = MFMA16F(a0, fr2[1],  e0);     \
            e1 = MFMA16F(a0, fr2[8],  zacc); e1 = MFMA16F(a0, fr2[9],  e1);     \
            e2 = MFMA16F(a0, fr2[16], zacc); e2 = MFMA16F(a0, fr2[17], e2);     \
            e3 = MFMA16F(a0, fr2[24], zacc); e3 = MFMA16F(a0, fr2[25], e3);     \
            e0 = MFMA16F(a1, fr2[2],  e0);   e0 = MFMA16F(a1, fr2[3],  e0);     \
            e1 = MFMA16F(a1, fr2[10], e1);   e1 = MFMA16F(a1, fr2[11], e1);     \
            e2 = MFMA16F(a1, fr2[18], e2);   e2 = MFMA16F(a1, fr2[19], e2);     \
            e3 = MFMA16F(a1, fr2[26], e3);   e3 = MFMA16F(a1, fr2[27], e3);     \
            e0 = MFMA16F(a2, fr2[4],  e0);   e0 = MFMA16F(a2, fr2[5],  e0);     \
            e1 = MFMA16F(a2, fr2[12], e1);   e1 = MFMA16F(a2, fr2[13], e1);     \
            e2 = MFMA16F(a2, fr2[20], e2);   e2 = MFMA16F(a2, fr2[21], e2);     \
            e3 = MFMA16F(a2, fr2[28], e3);   e3 = MFMA16F(a2, fr2[29], e3);     \
            e0 = MFMA16F(a3, fr2[6],  e0);   e0 = MFMA16F(a3, fr2[7],  e0);     \
            e1 = MFMA16F(a3, fr2[14], e1);   e1 = MFMA16F(a3, fr2[15], e1);     \
            e2 = MFMA16F(a3, fr2[22], e2);   e2 = MFMA16F(a3, fr2[23], e2);     \
            e3 = MFMA16F(a3, fr2[30], e3);   e3 = MFMA16F(a3, fr2[31], e3);     \
            floatx4 f0, f1, f2, f3;                                             \
            GTAIL(e0, f0, -) GTAIL(e1, f1, -) GTAIL(e2, f2, +) GTAIL(e3, f3, -) \
            _Pragma("unroll")                                                   \
            for (int r = 0; r < 4; r++) {                                       \
                float tgs = fmaf(-4.0f * L2E, f2[r], 2.0f * L2E);               \
                float cn  = fmaf(f1[r], cst2[r], f0[r] * tgs);                  \
                cst2[r] = cn;                                                   \
                float th = fmaf(-2.0f, rcp_fast(1.0f + exp2_fast(cn)), 1.0f);   \
                float hv = f3[r] * th;                                          \
                hv = uok ? hv : (uc == 51 ? 1.0f : 0.f);                        \
                int bb = q * 4 + r;                                             \
                if (bb < NB) {                                                  \
                    int wi = (((uc >> 1) + 4 * (bb >> 1)) & 31) * 2 + (uc & 1); \
                    ((unsigned short*)&h2[1 - (P)][bb][0])[wi] = f2h_bits(hv);  \
                }                                                               \
            }                                                                   \
        }                                                                       \
        __syncthreads();                                                        \
    } while (0)

    for (int itp = 0; itp < TT + 2; itp += 2) {
        STEP(itp, 0);
        STEP(itp + 1, 1);
    }
#undef STEP
#undef GTAIL
}

extern "C" void kernel_launch(void* const* d_in, const int* in_sizes, int n_in,
                              void* d_out, int out_size, void* d_ws, size_t ws_size,
                              hipStream_t stream) {
    const float* input = (const float*)d_in[0];
    const float* Wih1  = (const float*)d_in[1];
    const float* Whh1  = (const float*)d_in[2];
    const float* bih1  = (const float*)d_in[3];
    const float* bhh1  = (const float*)d_in[4];
    const float* Wih2  = (const float*)d_in[5];
    const float* Whh2  = (const float*)d_in[6];
    const float* bih2  = (const float*)d_in[7];
    const float* bhh2  = (const float*)d_in[8];
    const float* Wlin  = (const float*)d_in[9];
    const float* blin  = (const float*)d_in[10];

    uint4* frags = (uint4*)d_ws;            // 196 frags * 1 KiB
    int B = in_sizes[0] / TT;               // 4096

    lstm_prep<<<49, 256, 0, stream>>>(Whh1, Wih1, bih1, bhh1, Wih2, Whh2,
                                      bih2, bhh2, Wlin, blin, frags);
    lstm_main<<<B / NB, 256, 0, stream>>>(input, frags, (float*)d_out);
}